// Round 16
// baseline (2041.072 us; speedup 1.0000x reference)
//
#include <hip/hip_runtime.h>
#include <cstdint>
#include <cstddef>

#define L_SEQ   4096
#define BATCH   4
#define DIMM    768
#define D_INNER 1536
#define NHEADS  24
#define HEADDIM 64
#define D_STATE 16
#define CONVD   1568
#define D_IPROJ 3128
#define ZXP     3200     // padded zx row stride (6400B = 64B-aligned rows)
#define SEGLEN  64
#define NSEG    (L_SEQ / SEGLEN)   // 64
#define BCP     44       // BC LDS row stride (conflict-free, 8B-aligned)

typedef _Float16 f16x8 __attribute__((ext_vector_type(8)));
typedef _Float16 f16x4 __attribute__((ext_vector_type(4)));
typedef float    f32x4 __attribute__((ext_vector_type(4)));

__device__ __forceinline__ void glds16(const _Float16* g, _Float16* l) {
  __builtin_amdgcn_global_load_lds(
      (__attribute__((address_space(1))) unsigned int*)g,
      (__attribute__((address_space(3))) unsigned int*)l, 16, 0, 0);
}

__device__ __forceinline__ float fsilu(float x) {
  return x * __builtin_amdgcn_rcpf(1.f + __expf(-x));
}
__device__ __forceinline__ float fsig(float x) {
  return __builtin_amdgcn_rcpf(1.f + __expf(-x));
}

// ---------------------------------------------------------------------------
// 256x256x64 deep-pipelined f16 GEMM: 512 thr = 8 waves (2M x 4N), 128KB LDS
// double-buffer, global_load_lds staging (pre-swizzled source), 4 phases per
// K-tile {stage-next-half || ds_read frags || 16 MFMA}, single counted wait
// at phase 3 (loads hide under a full tile of compute). Epilogue: wave-
// private LDS transpose (XOR swizzle) -> 128B-contiguous f16x8 stores.
// OM: 0 = f16 out (+ col guard), 2 = f16 out + f32 bias.
// Requires: M % 256 == 0, (grid blocks) % 8 == 0, N % 8 == 0, K % 64 == 0.
// ---------------------------------------------------------------------------
template <int OM>
__global__ __launch_bounds__(512, 1) void gemm256(
    const _Float16* __restrict__ A, long lda,
    const _Float16* __restrict__ W,
    const float* __restrict__ bias,
    _Float16* __restrict__ C, long ldc,
    int M, int N, int K)
{
  __shared__ __align__(16) _Float16 lds[65536];   // A[2][16384] | B[2][16384]
  const int tid = threadIdx.x;
  const int lane = tid & 63, wid = tid >> 6;
  const int wm = wid >> 2, wn = wid & 3;
  const int la = lane & 15, lg = lane >> 4;
  const int srow = lane >> 3, schunk = lane & 7;

  const int nbx = gridDim.x, nby = gridDim.y;
  const int flat = blockIdx.y * nbx + blockIdx.x;
  const int xcd = flat & 7, idx = flat >> 3;
  const int rpx = nby >> 3;
  const long m0 = (long)(xcd * rpx + idx % rpx) * 256;
  const int n0 = (idx / rpx) * 256;

  const int nkt = K >> 6;

  // stage one half-tile: ht 0/1 = A halves, 2/3 = B halves (2 glds/thread)
  auto stage = [&](int buf, int ht, int kt) {
#pragma unroll
    for (int p = 0; p < 2; ++p) {
      int rg = wid * 2 + p;                        // 0..15
      int rl = (ht & 1) * 128 + rg * 8 + srow;     // local row 0..255
      int scn = schunk ^ (rl & 7);                 // pre-swizzled k-chunk
      const _Float16* src;
      if (ht < 2) {
        src = A + (m0 + rl) * lda + kt * 64 + scn * 8;
      } else {
        int n = n0 + rl; if (n >= N) n = N - 1;    // clamp (cols unstored)
        src = W + (long)n * (long)K + kt * 64 + scn * 8;
      }
      _Float16* dst = lds + (ht >= 2 ? 32768 : 0) + buf * 16384
                          + ((ht & 1) * 128 + rg * 8) * 64;
      glds16(src, dst);
    }
  };

  f32x4 acc[8][4] = {};

  // prologue: full tile 0 into buf 0
  stage(0, 0, 0); stage(0, 1, 0); stage(0, 2, 0); stage(0, 3, 0);
  asm volatile("s_waitcnt vmcnt(0)" ::: "memory");
  __syncthreads();

  int buf = 0;
  for (int kt = 0; kt < nkt; ++kt) {
    const bool nl = (kt + 1 < nkt);
    const _Float16* Ab = lds + buf * 16384;
    const _Float16* Bb = lds + 32768 + buf * 16384;
    f16x8 bfr[4][2];
#pragma unroll
    for (int ph = 0; ph < 4; ++ph) {
      if (nl) stage(buf ^ 1, ph, kt + 1);          // prefetch next tile
      if (ph == 0) {
#pragma unroll
        for (int j = 0; j < 4; ++j)
#pragma unroll
          for (int ks = 0; ks < 2; ++ks) {
            int rb = wn * 64 + j * 16 + la;
            int cc = ks * 4 + lg;
            bfr[j][ks] = *(const f16x8*)&Bb[rb * 64 + ((cc ^ (rb & 7)) << 3)];
          }
      }
      f16x8 af[2][2];
#pragma unroll
      for (int ii = 0; ii < 2; ++ii)
#pragma unroll
        for (int ks = 0; ks < 2; ++ks) {
          int ra = wm * 128 + (ph * 2 + ii) * 16 + la;
          int cc = ks * 4 + lg;
          af[ii][ks] = *(const f16x8*)&Ab[ra * 64 + ((cc ^ (ra & 7)) << 3)];
        }
      __builtin_amdgcn_s_setprio(1);
#pragma unroll
      for (int ii = 0; ii < 2; ++ii)
#pragma unroll
        for (int j = 0; j < 4; ++j)
#pragma unroll
          for (int ks = 0; ks < 2; ++ks)
            acc[ph * 2 + ii][j] = __builtin_amdgcn_mfma_f32_16x16x32_f16(
                af[ii][ks], bfr[j][ks], acc[ph * 2 + ii][j], 0, 0, 0);
      __builtin_amdgcn_s_setprio(0);
      if (ph == 3 && nl) asm volatile("s_waitcnt vmcnt(0)" ::: "memory");
      __syncthreads();
    }
    buf ^= 1;
  }

  // ---- epilogue: wave-private LDS transpose (XOR j-swizzle), f16x8 stores
  _Float16* ep = lds + wid * 8192;                 // [128][64]
#pragma unroll
  for (int i = 0; i < 8; ++i)
#pragma unroll
    for (int j = 0; j < 4; ++j) {
      float bs = 0.f;
      if (OM == 2) bs = bias[n0 + wn * 64 + j * 16 + la];
#pragma unroll
      for (int r = 0; r < 4; ++r) {
        int row = i * 16 + lg * 4 + r;
        int jj = j ^ (row & 3);
        ep[row * 64 + jj * 16 + la] = (_Float16)(acc[i][j][r] + bs);
      }
    }
  asm volatile("s_waitcnt lgkmcnt(0)" ::: "memory");
#pragma unroll
  for (int it = 0; it < 16; ++it) {
    int row = it * 8 + (lane >> 3);
    int hc = lane & 7;
    int jj = (hc >> 1) ^ (row & 3);
    f16x8 v = *(const f16x8*)&ep[row * 64 + jj * 16 + (hc & 1) * 8];
    int gcol = n0 + wn * 64 + hc * 8;
    long grow = m0 + wm * 128 + row;
    if (gcol < N)
      *(f16x8*)&C[grow * ldc + gcol] = v;
  }
}

// ---------------------------------------------------------------------------
// Old 128x128 GEMM kept for the head-out fusion (OM3 only).
// ---------------------------------------------------------------------------
template <int OM>
__global__ __launch_bounds__(256, 2) void gemm_mfma(
    const _Float16* __restrict__ A, int lda,
    const _Float16* __restrict__ W,
    const float* __restrict__ bias,
    void* __restrict__ Cv, long ldc, long extra,
    int M, int N, int K,
    const int* __restrict__ tidsp, int thead)
{
  __shared__ __align__(16) char smem[33792];
  _Float16* As = (_Float16*)smem;
  _Float16* Ws = (_Float16*)(smem + 16384);
  const int tid = threadIdx.x;
  const int lane = tid & 63, wid = tid >> 6;
  const int wr = wid >> 1, wc = wid & 1;

  const int nbx = gridDim.x, nby = gridDim.y;
  const int flat = blockIdx.y * nbx + blockIdx.x;
  const int xcd = flat & 7;
  const int bidx = flat >> 3;
  const int rpx = nby >> 3;
  const int rl = bidx % rpx;
  const int ct = bidx / rpx;
  const long m0 = (long)(xcd * rpx + rl) * 128;
  const int n0 = ct * 128;

  const int la = lane & 15, lg = lane >> 4;
  const int srow = lane >> 3, schunk = lane & 7;

  f32x4 acc[4][4] = {};

  for (int k0 = 0; k0 < K; k0 += 64) {
    __syncthreads();
#pragma unroll
    for (int p = 0; p < 4; ++p) {
      const int rg = (wid << 2) + p;
      const int row = (rg << 3) + srow;
      const int scn = schunk ^ (row & 7);
      glds16(A + (m0 + row) * (long)lda + k0 + scn * 8, As + rg * 512);
      int n = n0 + row; if (n >= N) n = N - 1;
      glds16(W + (long)n * K + k0 + scn * 8, Ws + rg * 512);
    }
    asm volatile("s_waitcnt vmcnt(0)" ::: "memory");
    __syncthreads();
#pragma unroll
    for (int ks = 0; ks < 2; ++ks) {
      const int cc = ks * 4 + lg;
      f16x8 af[4], bfr[4];
#pragma unroll
      for (int i = 0; i < 4; ++i) {
        int ra = wr * 64 + i * 16 + la;
        int rb = wc * 64 + i * 16 + la;
        af[i]  = *(const f16x8*)&As[ra * 64 + ((cc ^ (ra & 7)) << 3)];
        bfr[i] = *(const f16x8*)&Ws[rb * 64 + ((cc ^ (rb & 7)) << 3)];
      }
#pragma unroll
      for (int i = 0; i < 4; ++i)
#pragma unroll
        for (int j = 0; j < 4; ++j)
          acc[i][j] = __builtin_amdgcn_mfma_f32_16x16x32_f16(af[i], bfr[j], acc[i][j], 0, 0, 0);
    }
  }

  float* epi = (float*)smem;                    // [64][132]
#pragma unroll
  for (int ph = 0; ph < 2; ++ph) {
    __syncthreads();
    if (wr == ph) {
#pragma unroll
      for (int i = 0; i < 4; ++i)
#pragma unroll
        for (int j = 0; j < 4; ++j)
#pragma unroll
          for (int r = 0; r < 4; ++r)
            epi[(i * 16 + lg * 4 + r) * 132 + wc * 64 + j * 16 + la] = acc[i][j][r];
    }
    __syncthreads();
    if (OM == 3) {
      const int q = n0 >> 7;
      const int rr = tid >> 5;
      const int ch = tid & 31;
#pragma unroll
      for (int ps = 0; ps < 8; ++ps) {
        int lrow = ps * 8 + rr;
        long gr = m0 + ph * 64 + lrow;
        float keep = (tidsp[gr] == thead) ? 1.f : 0.f;
        float4 v = *(float4*)&epi[lrow * 132 + ch * 4];
        float o[4] = {v.x, v.y, v.z, v.w};
#pragma unroll
        for (int e = 0; e < 4; ++e) {
          float vv = o[e] + bias[n0 + ch * 4 + e];
          if (q != 0) vv = fsig(vv);
          o[e] = vv * keep;
        }
        *(float4*)((float*)Cv + (long)q * extra + gr * 128 + ch * 4) =
            make_float4(o[0], o[1], o[2], o[3]);
      }
    }
  }
}

// ---------------------------------------------------------------------------
__global__ __launch_bounds__(256) void cvt_kernel(
    const float* __restrict__ src, _Float16* __restrict__ dst, long n4)
{
  long i = (long)blockIdx.x * 256 + threadIdx.x;
  long stride = (long)gridDim.x * 256;
  for (; i < n4; i += stride) {
    float4 v = *(const float4*)(src + i * 4);
    f16x4 o = { (_Float16)v.x, (_Float16)v.y, (_Float16)v.z, (_Float16)v.w };
    *(f16x4*)(dst + i * 4) = o;
  }
}

__global__ __launch_bounds__(256) void pack_head_kernel(
    const float* __restrict__ how, const float* __restrict__ hob,
    _Float16* __restrict__ howb, float* __restrict__ hobp)
{
  const int wmap[4] = {0, 3, 1, 2};
  int idx = blockIdx.x * 256 + threadIdx.x;
  if (idx < 2 * 512 * 768) {
    int t = idx / (512 * 768);
    int rem = idx - t * 512 * 768;
    int q = rem / (128 * 768);
    int rem2 = rem - q * 128 * 768;
    howb[idx] = (_Float16)how[((size_t)(t * 4 + wmap[q])) * 128 * 768 + rem2];
  }
  if (idx < 1024) {
    int t = idx >> 9, rem = idx & 511;
    int q = rem >> 7, pp = rem & 127;
    hobp[idx] = hob[(t * 4 + wmap[q]) * 128 + pp];
  }
}

// ---------------------------------------------------------------------------
// SSD pass A (v3): log2-domain decay, fast silu, BC stride 44.
// ---------------------------------------------------------------------------
__global__ __launch_bounds__(64) void ssdA_kernel(
    const _Float16* __restrict__ zx, const float* __restrict__ cw,
    const float* __restrict__ cb, const float* __restrict__ dtb,
    const float* __restrict__ alog, const float* __restrict__ Dv,
    _Float16* __restrict__ ybuf, _Float16* __restrict__ bcbuf,
    float* __restrict__ Hseg, float* __restrict__ cumq)
{
  __shared__ __align__(16) char sm[14848];
  _Float16* XV    = (_Float16*)sm;           // [64][66] xconv (row=t)
  _Float16* bcraw = (_Float16*)sm;           // [67][32] alias (dead before XV)
  _Float16* BC    = (_Float16*)(sm + 8448);  // [64][BCP]: B 0..15, C 16..31
  float* sa  = (float*)(sm + 14080);         // log2-domain prefix decay
  float* sdt = (float*)(sm + 14336);
  float* sws = (float*)(sm + 14592);         // w[s]*dt[s]
  const int lane = threadIdx.x;
  const int seg = blockIdx.x & (NSEG - 1);
  const int bh = blockIdx.x >> 6;
  const int h = bh % NHEADS, b = bh / NHEADS;
  const int bl0 = b * L_SEQ + seg * SEGLEN;
  const float LOG2E = 1.44269504088896f;

  for (int i = lane; i < 67 * 4; i += 64) {
    int r = i >> 2, q = (i & 3) << 3;
    f16x8 v = {};
    if (seg > 0 || r >= 3)
      v = *(const f16x8*)&zx[(size_t)(bl0 - 3 + r) * ZXP + 2 * D_INNER + q];
    *(f16x8*)&bcraw[r * 32 + q] = v;
  }
  {
    float raw = (float)zx[(size_t)(bl0 + lane) * ZXP + (D_INNER + CONVD) + h] + dtb[h];
    float sp = (raw > 20.f) ? raw : log1pf(__expf(raw));
    sdt[lane] = sp;
    float av = __expf(alog[h]) * sp * LOG2E;   // log2-domain
#pragma unroll
    for (int off = 1; off < 64; off <<= 1) {
      float tv = __shfl_up(av, off, 64);
      if (lane >= off) av += tv;
    }
    sa[lane] = av;
    cumq[(size_t)bh * L_SEQ + seg * SEGLEN + lane] = exp2f(-av);
    float alast = __shfl(av, 63, 64);
    sws[lane] = exp2f(av - alast) * sp;
  }
  __syncthreads();

  for (int i = lane; i < SEGLEN * 32; i += 64) {
    int t = i >> 5, c = i & 31;
    float acc = cb[D_INNER + c];
#pragma unroll
    for (int k = 0; k < 4; ++k)
      acc = fmaf(cw[(D_INNER + c) * 4 + k], (float)bcraw[(t + k) * 32 + c], acc);
    _Float16 sh = (_Float16)fsilu(acc);
    BC[t * BCP + c] = sh;
    bcbuf[(size_t)(bl0 + t) * 32 + c] = sh;
  }
  __syncthreads();   // bcraw dead -> XV region reusable

  const int xch = h * HEADDIM + lane;
  const _Float16* xg = zx + (size_t)bl0 * ZXP + D_INNER + xch;
  const float cwx0 = cw[xch * 4 + 0], cwx1 = cw[xch * 4 + 1];
  const float cwx2 = cw[xch * 4 + 2], cwx3 = cw[xch * 4 + 3];
  const float cbx = cb[xch];
  float xw0 = 0.f, xw1 = 0.f, xw2 = 0.f;
  if (seg > 0) {
    xw0 = (float)xg[-3 * (long)ZXP];
    xw1 = (float)xg[-2 * (long)ZXP];
    xw2 = (float)xg[-1 * (long)ZXP];
  }
  float xcur = (float)xg[0];
  for (int t = 0; t < SEGLEN; ++t) {
    float xnext = (t < SEGLEN - 1) ? (float)xg[(size_t)(t + 1) * ZXP] : 0.f;
    float xa = cbx;
    xa = fmaf(cwx0, xw0, xa);
    xa = fmaf(cwx1, xw1, xa);
    xa = fmaf(cwx2, xw2, xa);
    xa = fmaf(cwx3, xcur, xa);
    XV[t * 66 + lane] = (_Float16)fsilu(xa);
    xw0 = xw1; xw1 = xw2; xw2 = xcur; xcur = xnext;
  }
  __syncthreads();

  const int la = lane & 15, lg = lane >> 4;

  f16x4 Mfrag[4][4];
  {
    f16x4 cf[4];
    float sat[4];
#pragma unroll
    for (int tt = 0; tt < 4; ++tt) {
      cf[tt] = *(const f16x4*)&BC[(tt * 16 + la) * BCP + 16 + lg * 4];
      sat[tt] = sa[tt * 16 + la];
    }
#pragma unroll
    for (int st = 0; st < 4; ++st) {
      f16x4 bfA = *(const f16x4*)&BC[(st * 16 + la) * BCP + lg * 4];
#pragma unroll
      for (int tt = 0; tt < 4; ++tt) {
        f32x4 a1 = {};
        a1 = __builtin_amdgcn_mfma_f32_16x16x16f16(bfA, cf[tt], a1, 0, 0, 0);
        f16x4 m;
#pragma unroll
        for (int r = 0; r < 4; ++r) {
          int s = st * 16 + lg * 4 + r;
          int t = tt * 16 + la;
          float mv = 0.f;
          if (s <= t) mv = a1[r] * exp2f(sa[s] - sat[tt]);
          m[r] = (_Float16)mv;
        }
        Mfrag[st][tt] = m;
      }
    }
  }

  f16x4 b3[4];
#pragma unroll
  for (int st = 0; st < 4; ++st) {
    f16x4 v;
#pragma unroll
    for (int e = 0; e < 4; ++e)
      v[e] = BC[(st * 16 + lg * 4 + e) * BCP + la];
    b3[st] = v;
  }

  const float Dh = Dv[h];
  float* Hst = Hseg + ((size_t)bh * NSEG + seg) * 1024;
#pragma unroll
  for (int pt = 0; pt < 4; ++pt) {
    f16x4 bf[4], af3[4];
#pragma unroll
    for (int st = 0; st < 4; ++st) {
      f16x4 v, w;
#pragma unroll
      for (int e = 0; e < 4; ++e) {
        int s = st * 16 + lg * 4 + e;
        float xv = (float)XV[s * 66 + pt * 16 + la];
        v[e] = (_Float16)(xv * sdt[s]);
        w[e] = (_Float16)(xv * sws[s]);
      }
      bf[st] = v; af3[st] = w;
    }
#pragma unroll
    for (int tt = 0; tt < 4; ++tt) {
      f32x4 a2 = {};
#pragma unroll
      for (int st = 0; st < 4; ++st)
        a2 = __builtin_amdgcn_mfma_f32_16x16x16f16(Mfrag[st][tt], bf[st], a2, 0, 0, 0);
#pragma unroll
      for (int r = 0; r < 4; ++r) {
        int t = tt * 16 + lg * 4 + r, p = pt * 16 + la;
        float y = a2[r] + Dh * (float)XV[t * 66 + p];
        ybuf[(size_t)(bl0 + t) * D_INNER + h * HEADDIM + p] = (_Float16)y;
      }
    }
    f32x4 a3 = {};
#pragma unroll
    for (int st = 0; st < 4; ++st)
      a3 = __builtin_amdgcn_mfma_f32_16x16x16f16(af3[st], b3[st], a3, 0, 0, 0);
#pragma unroll
    for (int r = 0; r < 4; ++r) {
      int p = pt * 16 + lg * 4 + r;
      Hst[p * 16 + la] = a3[r];
    }
  }
}

// ---------------------------------------------------------------------------
__global__ __launch_bounds__(1024) void scanB_kernel(
    float* __restrict__ Hseg, const float* __restrict__ cumq)
{
  const int bh = blockIdx.x;
  const int t = threadIdx.x;
  __shared__ float sp[NSEG];
  if (t < NSEG) sp[t] = cumq[(size_t)bh * L_SEQ + t * SEGLEN + (SEGLEN - 1)];
  __syncthreads();
  float v[NSEG];
#pragma unroll
  for (int s = 0; s < NSEG; ++s)
    v[s] = Hseg[((size_t)bh * NSEG + s) * 1024 + t];
  float h = 0.f;
#pragma unroll
  for (int s = 0; s < NSEG; ++s) {
    Hseg[((size_t)bh * NSEG + s) * 1024 + t] = h;
    h = fmaf(sp[s], h, v[s]);
  }
}

// ---------------------------------------------------------------------------
__global__ __launch_bounds__(64) void ssdC_kernel(
    _Float16* __restrict__ ybuf, const _Float16* __restrict__ bcbuf,
    const float* __restrict__ Hseg, const float* __restrict__ cumq)
{
  const int seg = blockIdx.x & (NSEG - 1);
  if (seg == 0) return;
  const int lane = threadIdx.x;
  const int bh = blockIdx.x >> 6;
  const int h = bh % NHEADS, b = bh / NHEADS;
  const int bl0 = b * L_SEQ + seg * SEGLEN;
  __shared__ float scq[SEGLEN];
  scq[lane] = cumq[(size_t)bh * L_SEQ + seg * SEGLEN + lane];
  const int la = lane & 15, lg = lane >> 4;
  const float* slot = Hseg + ((size_t)bh * NSEG + seg) * 1024;

  f16x8 a4[4], w4[4];
#pragma unroll
  for (int i = 0; i < 4; ++i) {
    f16x8 v = {};
    if (lg < 2)
      v = *(const f16x8*)&bcbuf[(size_t)(bl0 + i * 16 + la) * 32 + 16 + lg * 8];
    a4[i] = v;
  }
#pragma unroll
  for (int j = 0; j < 4; ++j) {
    f16x8 v = {};
    if (lg < 2) {
#pragma unroll
      for (int e = 0; e < 8; ++e)
        v[e] = (_Float16)slot[(j * 16 + la) * 16 + lg * 8 + e];
    }
    w4[j] = v;
  }
  f32x4 acc[4][4] = {};
#pragma unroll
  for (int i = 0; i < 4; ++i)
#pragma unroll
    for (int j = 0; j < 4; ++j)
      acc[i][j] = __builtin_amdgcn_mfma_f32_16x16x32_f16(a4[i], w4[j], acc[i][j], 0, 0, 0);
  __syncthreads();
#pragma unroll
  for (int i = 0; i < 4; ++i)
#pragma unroll
    for (int j = 0; j < 4; ++j)
#pragma unroll
      for (int r = 0; r < 4; ++r) {
        int t = i * 16 + lg * 4 + r, p = j * 16 + la;
        size_t ad = (size_t)(bl0 + t) * D_INNER + h * HEADDIM + p;
        ybuf[ad] = (_Float16)((float)ybuf[ad] + scq[t] * acc[i][j][r]);
      }
}

// ---------------------------------------------------------------------------
__global__ __launch_bounds__(256) void norm_kernel(
    const _Float16* __restrict__ y, _Float16* __restrict__ zx,
    const float* __restrict__ nw)
{
  const int row = blockIdx.x;
  const int tid = threadIdx.x;
  const _Float16* yr = y + (size_t)row * D_INNER;
  _Float16* zr = zx + (size_t)row * ZXP;
  float v[6];
  float ss = 0.f;
#pragma unroll
  for (int jj = 0; jj < 6; ++jj) {
    int c = jj * 256 + tid;
    float yv = (float)yr[c];
    float zv = (float)zr[c];
    float val = yv * fsilu(zv);
    v[jj] = val;
    ss = fmaf(val, val, ss);
  }
#pragma unroll
  for (int off = 32; off > 0; off >>= 1) ss += __shfl_xor(ss, off, 64);
  __shared__ float red[4];
  if ((tid & 63) == 0) red[tid >> 6] = ss;
  __syncthreads();
  float tot = red[0] + red[1] + red[2] + red[3];
  float rs = rsqrtf(tot * (1.f / 1536.f) + 1e-5f);
#pragma unroll
  for (int jj = 0; jj < 6; ++jj) {
    int c = jj * 256 + tid;
    zr[c] = (_Float16)(v[jj] * rs * nw[c]);
  }
}

// ---------------------------------------------------------------------------
extern "C" void kernel_launch(void* const* d_in, const int* in_sizes, int n_in,
                              void* d_out, int out_size, void* d_ws, size_t ws_size,
                              hipStream_t stream)
{
  const float* x_in = (const float*)d_in[0];
  const int*   tids = (const int*)d_in[1];
  const float* ipw  = (const float*)d_in[2];
  const float* cw   = (const float*)d_in[3];
  const float* cb   = (const float*)d_in[4];
  const float* dtb  = (const float*)d_in[5];
  const float* alog = (const float*)d_in[6];
  const float* Dv   = (const float*)d_in[7];
  const float* nw   = (const float*)d_in[8];
  const float* opw  = (const float*)d_in[9];
  const float* hw   = (const float*)d_in[10];
  const float* hb   = (const float*)d_in[11];
  const float* how  = (const float*)d_in[12];
  const float* hob  = (const float*)d_in[13];
  float* out = (float*)d_out;

  char* p = (char*)d_ws;
  _Float16* ipw_b = (_Float16*)p; p += (size_t)14413824 * 2;
  _Float16* opw_b = (_Float16*)p; p += (size_t)7077888 * 2;
  _Float16* hw_b  = (_Float16*)p; p += (size_t)1179648 * 2;
  _Float16* how_b = (_Float16*)p; p += (size_t)786432 * 2;
  float*    hob_p = (float*)p;    p += (size_t)1024 * 4;
  const size_t used_w = (size_t)(p - (char*)d_ws);
  const size_t PB = 54528000;
  int nb = 4;
  while (nb > 1 && used_w + (size_t)nb * PB > ws_size) nb >>= 1;

  cvt_kernel<<<8192, 256, 0, stream>>>(ipw, ipw_b, 14413824 / 4);
  cvt_kernel<<<6912, 256, 0, stream>>>(opw, opw_b, 7077888 / 4);
  cvt_kernel<<<1152, 256, 0, stream>>>(hw, hw_b, 1179648 / 4);
  pack_head_kernel<<<3072, 256, 0, stream>>>(how, hob, how_b, hob_p);

  for (int b0 = 0; b0 < BATCH; b0 += nb) {
    const int MT = nb * L_SEQ;
    _Float16* zx    = (_Float16*)p;
    _Float16* ybuf  = zx + (size_t)MT * ZXP;
    _Float16* bcbuf = ybuf + (size_t)MT * D_INNER;
    float*    Hseg  = (float*)(bcbuf + (size_t)MT * 32);
    float*    cumq  = Hseg + (size_t)nb * NHEADS * NSEG * 1024;
    _Float16* xbuf  = (_Float16*)(cumq + (size_t)MT * NHEADS);
    _Float16* hbuf  = zx;

    cvt_kernel<<<6144, 256, 0, stream>>>(x_in + (size_t)b0 * L_SEQ * DIMM,
                                         xbuf, (long)MT * DIMM / 4);

    for (int i = 0; i < 6; ++i) {
      gemm256<0><<<dim3(13, MT / 256), 512, 0, stream>>>(
          xbuf, DIMM, ipw_b + (size_t)i * D_IPROJ * DIMM, nullptr,
          zx, ZXP, MT, D_IPROJ, DIMM);
      ssdA_kernel<<<nb * NHEADS * NSEG, 64, 0, stream>>>(
          zx, cw + (size_t)i * CONVD * 4, cb + i * CONVD,
          dtb + i * NHEADS, alog + i * NHEADS, Dv + i * NHEADS,
          ybuf, bcbuf, Hseg, cumq);
      scanB_kernel<<<nb * NHEADS, 1024, 0, stream>>>(Hseg, cumq);
      ssdC_kernel<<<nb * NHEADS * NSEG, 64, 0, stream>>>(ybuf, bcbuf, Hseg, cumq);
      norm_kernel<<<MT, 256, 0, stream>>>(ybuf, zx, nw + i * D_INNER);
      gemm256<0><<<dim3(3, MT / 256), 512, 0, stream>>>(
          zx, ZXP, opw_b + (size_t)i * DIMM * D_INNER, nullptr,
          xbuf, DIMM, MT, DIMM, D_INNER);
    }

    for (int t = 0; t < 2; ++t) {
      gemm256<2><<<dim3(3, MT / 256), 512, 0, stream>>>(
          xbuf, DIMM, hw_b + (size_t)t * DIMM * DIMM, hb + t * DIMM,
          hbuf, DIMM, MT, DIMM, DIMM);
      gemm_mfma<3><<<dim3(4, MT / 128), 256, 0, stream>>>(
          hbuf, DIMM, how_b + (size_t)t * 512 * DIMM, hob_p + t * 512,
          out + (size_t)t * 4 * 16384 * 128 + (size_t)b0 * L_SEQ * 128,
          128, (long)16384 * 128, MT, 512, DIMM,
          tids + (size_t)b0 * L_SEQ, t);
    }
  }
}

// Round 17
// 1867.433 us; speedup vs baseline: 1.0930x; 1.0930x over previous
//
#include <hip/hip_runtime.h>
#include <cstdint>
#include <cstddef>

#define L_SEQ   4096
#define BATCH   4
#define DIMM    768
#define D_INNER 1536
#define NHEADS  24
#define HEADDIM 64
#define D_STATE 16
#define CONVD   1568
#define D_IPROJ 3128
#define ZXP     3200     // padded zx row stride (6400B = 64B-aligned rows)
#define SEGLEN  64
#define NSEG    (L_SEQ / SEGLEN)   // 64
#define BCP     44       // BC LDS row stride (conflict-free, 8B-aligned)

typedef _Float16 f16x8 __attribute__((ext_vector_type(8)));
typedef _Float16 f16x4 __attribute__((ext_vector_type(4)));
typedef float    f32x4 __attribute__((ext_vector_type(4)));

__device__ __forceinline__ void glds16(const _Float16* g, _Float16* l) {
  __builtin_amdgcn_global_load_lds(
      (__attribute__((address_space(1))) unsigned int*)g,
      (__attribute__((address_space(3))) unsigned int*)l, 16, 0, 0);
}

__device__ __forceinline__ float fsilu(float x) {
  return x * __builtin_amdgcn_rcpf(1.f + __expf(-x));
}
__device__ __forceinline__ float fsig(float x) {
  return __builtin_amdgcn_rcpf(1.f + __expf(-x));
}

// ---------------------------------------------------------------------------
// 256x256x64 pipelined f16 GEMM v3: 512 thr = 8 waves (2M x 4N), 128KB LDS
// double buffer. Per K-tile: {issue 8 wave-local glds for tile k+1 ->
// 64 MFMAs from tile k -> vmcnt(0) -> RAW s_barrier}. Loads overlap the
// whole tile's compute; ONE barrier per tile; no implicit vmcnt drains.
// Wave-local staging: each wave stages exactly the A-half / B-half it reads,
// so per-wave vmcnt(0) + barrier = race-free handoff.
// Epilogue: wave-private LDS transpose with (c ^ ((row&7)<<3)) swizzle.
// OM: 0 = f16 out (+ col guard), 2 = f16 out + f32 bias.
// Requires M % 256 == 0, grid-blocks % 8 == 0 (nby % 8 == 0), K % 64 == 0.
// ---------------------------------------------------------------------------
template <int OM>
__global__ __launch_bounds__(512, 1) void gemm256(
    const _Float16* __restrict__ A, long lda,
    const _Float16* __restrict__ W,
    const float* __restrict__ bias,
    _Float16* __restrict__ C, long ldc,
    int M, int N, int K)
{
  __shared__ __align__(16) _Float16 lds[65536];  // buf b: A at b*32768, B at +16384
  const int tid = threadIdx.x;
  const int lane = tid & 63, wid = tid >> 6;
  const int wm = wid >> 2, wn = wid & 3;
  const int la = lane & 15, lg = lane >> 4;
  const int srow = lane >> 3, schunk = lane & 7;
  const int ga = wid & 3;                 // A-group subindex (4 waves per A-half)
  const int hb = wn >> 1;                 // B-half this wave stages AND reads
  const int gb = (wm << 1) | (wn & 1);    // B-group subindex

  const int nbx = gridDim.x, nby = gridDim.y;
  const int flat = blockIdx.y * nbx + blockIdx.x;
  const int xcd = flat & 7, idx = flat >> 3;
  const int rpx = nby >> 3;
  const long m0 = (long)(xcd * rpx + idx % rpx) * 256;
  const int n0 = (idx / rpx) * 256;
  const int nkt = K >> 6;

  auto stage = [&](int buf, int kt) {
    _Float16* Ab = lds + buf * 32768;
    _Float16* Bb = lds + buf * 32768 + 16384;
#pragma unroll
    for (int q = 0; q < 4; ++q) {
      int rla = wm * 128 + (ga * 4 + q) * 8;       // 8-row group (A)
      int row = rla + srow;
      int scn = schunk ^ (row & 7);
      glds16(A + (m0 + row) * lda + kt * 64 + scn * 8, Ab + rla * 64);
      int rlb = hb * 128 + (gb * 4 + q) * 8;       // 8-row group (B)
      int rowb = rlb + srow;
      int n = n0 + rowb; if (n >= N) n = N - 1;
      int scnb = schunk ^ (rowb & 7);
      glds16(W + (long)n * (long)K + kt * 64 + scnb * 8, Bb + rlb * 64);
    }
  };

  f32x4 acc[8][4] = {};

  stage(0, 0);
  asm volatile("s_waitcnt vmcnt(0)" ::: "memory");
  __builtin_amdgcn_s_barrier();

  int buf = 0;
  for (int kt = 0; kt < nkt; ++kt) {
    if (kt + 1 < nkt) stage(buf ^ 1, kt + 1);      // issue-early
    const _Float16* Ab = lds + buf * 32768;
    const _Float16* Bb = lds + buf * 32768 + 16384;
    f16x8 bfr[4][2];
#pragma unroll
    for (int j = 0; j < 4; ++j)
#pragma unroll
      for (int ks = 0; ks < 2; ++ks) {
        int rb = wn * 64 + j * 16 + la;
        int cc = ks * 4 + lg;
        bfr[j][ks] = *(const f16x8*)&Bb[rb * 64 + ((cc ^ (rb & 7)) << 3)];
      }
#pragma unroll
    for (int m = 0; m < 8; ++m) {
      f16x8 am[2];
#pragma unroll
      for (int ks = 0; ks < 2; ++ks) {
        int ra = wm * 128 + m * 16 + la;
        int cc = ks * 4 + lg;
        am[ks] = *(const f16x8*)&Ab[ra * 64 + ((cc ^ (ra & 7)) << 3)];
      }
      __builtin_amdgcn_s_setprio(1);
#pragma unroll
      for (int j = 0; j < 4; ++j)
#pragma unroll
        for (int ks = 0; ks < 2; ++ks)
          acc[m][j] = __builtin_amdgcn_mfma_f32_16x16x32_f16(
              am[ks], bfr[j][ks], acc[m][j], 0, 0, 0);
      __builtin_amdgcn_s_setprio(0);
    }
    if (kt + 1 < nkt) asm volatile("s_waitcnt vmcnt(0)" ::: "memory");  // wait-late
    __builtin_amdgcn_s_barrier();
    buf ^= 1;
  }

  // ---- epilogue: wave-private transpose, swizzled, f16x8 row stores ----
  _Float16* ep = lds + wid * 8192;                 // [128][64] halfwords
#pragma unroll
  for (int m = 0; m < 8; ++m)
#pragma unroll
    for (int j = 0; j < 4; ++j) {
      float bs = 0.f;
      if (OM == 2) bs = bias[n0 + wn * 64 + j * 16 + la];
#pragma unroll
      for (int r = 0; r < 4; ++r) {
        int row = m * 16 + lg * 4 + r;
        int c = j * 16 + la;
        ep[row * 64 + (c ^ ((row & 7) << 3))] = (_Float16)(acc[m][j][r] + bs);
      }
    }
  asm volatile("s_waitcnt lgkmcnt(0)" ::: "memory");
  __builtin_amdgcn_sched_barrier(0);
#pragma unroll
  for (int it = 0; it < 16; ++it) {
    int row = it * 8 + (lane >> 3);
    int c0 = (lane & 7) * 8;
    f16x8 v = *(const f16x8*)&ep[row * 64 + (c0 ^ ((row & 7) << 3))];
    long grow = m0 + wm * 128 + row;
    int gcol = n0 + wn * 64 + c0;
    if (gcol < N) *(f16x8*)&C[grow * ldc + gcol] = v;
  }
}

// ---------------------------------------------------------------------------
// 128x128 GEMM kept for the head-out fusion (OM3 only).
// ---------------------------------------------------------------------------
template <int OM>
__global__ __launch_bounds__(256, 2) void gemm_mfma(
    const _Float16* __restrict__ A, int lda,
    const _Float16* __restrict__ W,
    const float* __restrict__ bias,
    void* __restrict__ Cv, long ldc, long extra,
    int M, int N, int K,
    const int* __restrict__ tidsp, int thead)
{
  __shared__ __align__(16) char smem[33792];
  _Float16* As = (_Float16*)smem;
  _Float16* Ws = (_Float16*)(smem + 16384);
  const int tid = threadIdx.x;
  const int lane = tid & 63, wid = tid >> 6;
  const int wr = wid >> 1, wc = wid & 1;

  const int nbx = gridDim.x, nby = gridDim.y;
  const int flat = blockIdx.y * nbx + blockIdx.x;
  const int xcd = flat & 7;
  const int bidx = flat >> 3;
  const int rpx = nby >> 3;
  const int rl = bidx % rpx;
  const int ct = bidx / rpx;
  const long m0 = (long)(xcd * rpx + rl) * 128;
  const int n0 = ct * 128;

  const int la = lane & 15, lg = lane >> 4;
  const int srow = lane >> 3, schunk = lane & 7;

  f32x4 acc[4][4] = {};

  for (int k0 = 0; k0 < K; k0 += 64) {
    __syncthreads();
#pragma unroll
    for (int p = 0; p < 4; ++p) {
      const int rg = (wid << 2) + p;
      const int row = (rg << 3) + srow;
      const int scn = schunk ^ (row & 7);
      glds16(A + (m0 + row) * (long)lda + k0 + scn * 8, As + rg * 512);
      int n = n0 + row; if (n >= N) n = N - 1;
      glds16(W + (long)n * K + k0 + scn * 8, Ws + rg * 512);
    }
    asm volatile("s_waitcnt vmcnt(0)" ::: "memory");
    __syncthreads();
#pragma unroll
    for (int ks = 0; ks < 2; ++ks) {
      const int cc = ks * 4 + lg;
      f16x8 af[4], bfr[4];
#pragma unroll
      for (int i = 0; i < 4; ++i) {
        int ra = wr * 64 + i * 16 + la;
        int rb = wc * 64 + i * 16 + la;
        af[i]  = *(const f16x8*)&As[ra * 64 + ((cc ^ (ra & 7)) << 3)];
        bfr[i] = *(const f16x8*)&Ws[rb * 64 + ((cc ^ (rb & 7)) << 3)];
      }
#pragma unroll
      for (int i = 0; i < 4; ++i)
#pragma unroll
        for (int j = 0; j < 4; ++j)
          acc[i][j] = __builtin_amdgcn_mfma_f32_16x16x32_f16(af[i], bfr[j], acc[i][j], 0, 0, 0);
    }
  }

  float* epi = (float*)smem;                    // [64][132]
#pragma unroll
  for (int ph = 0; ph < 2; ++ph) {
    __syncthreads();
    if (wr == ph) {
#pragma unroll
      for (int i = 0; i < 4; ++i)
#pragma unroll
        for (int j = 0; j < 4; ++j)
#pragma unroll
          for (int r = 0; r < 4; ++r)
            epi[(i * 16 + lg * 4 + r) * 132 + wc * 64 + j * 16 + la] = acc[i][j][r];
    }
    __syncthreads();
    if (OM == 3) {
      const int q = n0 >> 7;
      const int rr = tid >> 5;
      const int ch = tid & 31;
#pragma unroll
      for (int ps = 0; ps < 8; ++ps) {
        int lrow = ps * 8 + rr;
        long gr = m0 + ph * 64 + lrow;
        float keep = (tidsp[gr] == thead) ? 1.f : 0.f;
        float4 v = *(float4*)&epi[lrow * 132 + ch * 4];
        float o[4] = {v.x, v.y, v.z, v.w};
#pragma unroll
        for (int e = 0; e < 4; ++e) {
          float vv = o[e] + bias[n0 + ch * 4 + e];
          if (q != 0) vv = fsig(vv);
          o[e] = vv * keep;
        }
        *(float4*)((float*)Cv + (long)q * extra + gr * 128 + ch * 4) =
            make_float4(o[0], o[1], o[2], o[3]);
      }
    }
  }
}

// ---------------------------------------------------------------------------
__global__ __launch_bounds__(256) void cvt_kernel(
    const float* __restrict__ src, _Float16* __restrict__ dst, long n4)
{
  long i = (long)blockIdx.x * 256 + threadIdx.x;
  long stride = (long)gridDim.x * 256;
  for (; i < n4; i += stride) {
    float4 v = *(const float4*)(src + i * 4);
    f16x4 o = { (_Float16)v.x, (_Float16)v.y, (_Float16)v.z, (_Float16)v.w };
    *(f16x4*)(dst + i * 4) = o;
  }
}

__global__ __launch_bounds__(256) void pack_head_kernel(
    const float* __restrict__ how, const float* __restrict__ hob,
    _Float16* __restrict__ howb, float* __restrict__ hobp)
{
  const int wmap[4] = {0, 3, 1, 2};
  int idx = blockIdx.x * 256 + threadIdx.x;
  if (idx < 2 * 512 * 768) {
    int t = idx / (512 * 768);
    int rem = idx - t * 512 * 768;
    int q = rem / (128 * 768);
    int rem2 = rem - q * 128 * 768;
    howb[idx] = (_Float16)how[((size_t)(t * 4 + wmap[q])) * 128 * 768 + rem2];
  }
  if (idx < 1024) {
    int t = idx >> 9, rem = idx & 511;
    int q = rem >> 7, pp = rem & 127;
    hobp[idx] = hob[(t * 4 + wmap[q]) * 128 + pp];
  }
}

// ---------------------------------------------------------------------------
// SSD pass A (v3): log2-domain decay, fast silu, BC stride 44.
// ---------------------------------------------------------------------------
__global__ __launch_bounds__(64) void ssdA_kernel(
    const _Float16* __restrict__ zx, const float* __restrict__ cw,
    const float* __restrict__ cb, const float* __restrict__ dtb,
    const float* __restrict__ alog, const float* __restrict__ Dv,
    _Float16* __restrict__ ybuf, _Float16* __restrict__ bcbuf,
    float* __restrict__ Hseg, float* __restrict__ cumq)
{
  __shared__ __align__(16) char sm[14848];
  _Float16* XV    = (_Float16*)sm;           // [64][66] xconv (row=t)
  _Float16* bcraw = (_Float16*)sm;           // [67][32] alias (dead before XV)
  _Float16* BC    = (_Float16*)(sm + 8448);  // [64][BCP]: B 0..15, C 16..31
  float* sa  = (float*)(sm + 14080);         // log2-domain prefix decay
  float* sdt = (float*)(sm + 14336);
  float* sws = (float*)(sm + 14592);         // w[s]*dt[s]
  const int lane = threadIdx.x;
  const int seg = blockIdx.x & (NSEG - 1);
  const int bh = blockIdx.x >> 6;
  const int h = bh % NHEADS, b = bh / NHEADS;
  const int bl0 = b * L_SEQ + seg * SEGLEN;
  const float LOG2E = 1.44269504088896f;

  for (int i = lane; i < 67 * 4; i += 64) {
    int r = i >> 2, q = (i & 3) << 3;
    f16x8 v = {};
    if (seg > 0 || r >= 3)
      v = *(const f16x8*)&zx[(size_t)(bl0 - 3 + r) * ZXP + 2 * D_INNER + q];
    *(f16x8*)&bcraw[r * 32 + q] = v;
  }
  {
    float raw = (float)zx[(size_t)(bl0 + lane) * ZXP + (D_INNER + CONVD) + h] + dtb[h];
    float sp = (raw > 20.f) ? raw : log1pf(__expf(raw));
    sdt[lane] = sp;
    float av = __expf(alog[h]) * sp * LOG2E;   // log2-domain
#pragma unroll
    for (int off = 1; off < 64; off <<= 1) {
      float tv = __shfl_up(av, off, 64);
      if (lane >= off) av += tv;
    }
    sa[lane] = av;
    cumq[(size_t)bh * L_SEQ + seg * SEGLEN + lane] = exp2f(-av);
    float alast = __shfl(av, 63, 64);
    sws[lane] = exp2f(av - alast) * sp;
  }
  __syncthreads();

  for (int i = lane; i < SEGLEN * 32; i += 64) {
    int t = i >> 5, c = i & 31;
    float acc = cb[D_INNER + c];
#pragma unroll
    for (int k = 0; k < 4; ++k)
      acc = fmaf(cw[(D_INNER + c) * 4 + k], (float)bcraw[(t + k) * 32 + c], acc);
    _Float16 sh = (_Float16)fsilu(acc);
    BC[t * BCP + c] = sh;
    bcbuf[(size_t)(bl0 + t) * 32 + c] = sh;
  }
  __syncthreads();   // bcraw dead -> XV region reusable

  const int xch = h * HEADDIM + lane;
  const _Float16* xg = zx + (size_t)bl0 * ZXP + D_INNER + xch;
  const float cwx0 = cw[xch * 4 + 0], cwx1 = cw[xch * 4 + 1];
  const float cwx2 = cw[xch * 4 + 2], cwx3 = cw[xch * 4 + 3];
  const float cbx = cb[xch];
  float xw0 = 0.f, xw1 = 0.f, xw2 = 0.f;
  if (seg > 0) {
    xw0 = (float)xg[-3 * (long)ZXP];
    xw1 = (float)xg[-2 * (long)ZXP];
    xw2 = (float)xg[-1 * (long)ZXP];
  }
  float xcur = (float)xg[0];
  for (int t = 0; t < SEGLEN; ++t) {
    float xnext = (t < SEGLEN - 1) ? (float)xg[(size_t)(t + 1) * ZXP] : 0.f;
    float xa = cbx;
    xa = fmaf(cwx0, xw0, xa);
    xa = fmaf(cwx1, xw1, xa);
    xa = fmaf(cwx2, xw2, xa);
    xa = fmaf(cwx3, xcur, xa);
    XV[t * 66 + lane] = (_Float16)fsilu(xa);
    xw0 = xw1; xw1 = xw2; xw2 = xcur; xcur = xnext;
  }
  __syncthreads();

  const int la = lane & 15, lg = lane >> 4;

  f16x4 Mfrag[4][4];
  {
    f16x4 cf[4];
    float sat[4];
#pragma unroll
    for (int tt = 0; tt < 4; ++tt) {
      cf[tt] = *(const f16x4*)&BC[(tt * 16 + la) * BCP + 16 + lg * 4];
      sat[tt] = sa[tt * 16 + la];
    }
#pragma unroll
    for (int st = 0; st < 4; ++st) {
      f16x4 bfA = *(const f16x4*)&BC[(st * 16 + la) * BCP + lg * 4];
#pragma unroll
      for (int tt = 0; tt < 4; ++tt) {
        f32x4 a1 = {};
        a1 = __builtin_amdgcn_mfma_f32_16x16x16f16(bfA, cf[tt], a1, 0, 0, 0);
        f16x4 m;
#pragma unroll
        for (int r = 0; r < 4; ++r) {
          int s = st * 16 + lg * 4 + r;
          int t = tt * 16 + la;
          float mv = 0.f;
          if (s <= t) mv = a1[r] * exp2f(sa[s] - sat[tt]);
          m[r] = (_Float16)mv;
        }
        Mfrag[st][tt] = m;
      }
    }
  }

  f16x4 b3[4];
#pragma unroll
  for (int st = 0; st < 4; ++st) {
    f16x4 v;
#pragma unroll
    for (int e = 0; e < 4; ++e)
      v[e] = BC[(st * 16 + lg * 4 + e) * BCP + la];
    b3[st] = v;
  }

  const float Dh = Dv[h];
  float* Hst = Hseg + ((size_t)bh * NSEG + seg) * 1024;
#pragma unroll
  for (int pt = 0; pt < 4; ++pt) {
    f16x4 bf[4], af3[4];
#pragma unroll
    for (int st = 0; st < 4; ++st) {
      f16x4 v, w;
#pragma unroll
      for (int e = 0; e < 4; ++e) {
        int s = st * 16 + lg * 4 + e;
        float xv = (float)XV[s * 66 + pt * 16 + la];
        v[e] = (_Float16)(xv * sdt[s]);
        w[e] = (_Float16)(xv * sws[s]);
      }
      bf[st] = v; af3[st] = w;
    }
#pragma unroll
    for (int tt = 0; tt < 4; ++tt) {
      f32x4 a2 = {};
#pragma unroll
      for (int st = 0; st < 4; ++st)
        a2 = __builtin_amdgcn_mfma_f32_16x16x16f16(Mfrag[st][tt], bf[st], a2, 0, 0, 0);
#pragma unroll
      for (int r = 0; r < 4; ++r) {
        int t = tt * 16 + lg * 4 + r, p = pt * 16 + la;
        float y = a2[r] + Dh * (float)XV[t * 66 + p];
        ybuf[(size_t)(bl0 + t) * D_INNER + h * HEADDIM + p] = (_Float16)y;
      }
    }
    f32x4 a3 = {};
#pragma unroll
    for (int st = 0; st < 4; ++st)
      a3 = __builtin_amdgcn_mfma_f32_16x16x16f16(af3[st], b3[st], a3, 0, 0, 0);
#pragma unroll
    for (int r = 0; r < 4; ++r) {
      int p = pt * 16 + lg * 4 + r;
      Hst[p * 16 + la] = a3[r];
    }
  }
}

// ---------------------------------------------------------------------------
__global__ __launch_bounds__(1024) void scanB_kernel(
    float* __restrict__ Hseg, const float* __restrict__ cumq)
{
  const int bh = blockIdx.x;
  const int t = threadIdx.x;
  __shared__ float sp[NSEG];
  if (t < NSEG) sp[t] = cumq[(size_t)bh * L_SEQ + t * SEGLEN + (SEGLEN - 1)];
  __syncthreads();
  float v[NSEG];
#pragma unroll
  for (int s = 0; s < NSEG; ++s)
    v[s] = Hseg[((size_t)bh * NSEG + s) * 1024 + t];
  float h = 0.f;
#pragma unroll
  for (int s = 0; s < NSEG; ++s) {
    Hseg[((size_t)bh * NSEG + s) * 1024 + t] = h;
    h = fmaf(sp[s], h, v[s]);
  }
}

// ---------------------------------------------------------------------------
__global__ __launch_bounds__(64) void ssdC_kernel(
    _Float16* __restrict__ ybuf, const _Float16* __restrict__ bcbuf,
    const float* __restrict__ Hseg, const float* __restrict__ cumq)
{
  const int seg = blockIdx.x & (NSEG - 1);
  if (seg == 0) return;
  const int lane = threadIdx.x;
  const int bh = blockIdx.x >> 6;
  const int h = bh % NHEADS, b = bh / NHEADS;
  const int bl0 = b * L_SEQ + seg * SEGLEN;
  __shared__ float scq[SEGLEN];
  scq[lane] = cumq[(size_t)bh * L_SEQ + seg * SEGLEN + lane];
  const int la = lane & 15, lg = lane >> 4;
  const float* slot = Hseg + ((size_t)bh * NSEG + seg) * 1024;

  f16x8 a4[4], w4[4];
#pragma unroll
  for (int i = 0; i < 4; ++i) {
    f16x8 v = {};
    if (lg < 2)
      v = *(const f16x8*)&bcbuf[(size_t)(bl0 + i * 16 + la) * 32 + 16 + lg * 8];
    a4[i] = v;
  }
#pragma unroll
  for (int j = 0; j < 4; ++j) {
    f16x8 v = {};
    if (lg < 2) {
#pragma unroll
      for (int e = 0; e < 8; ++e)
        v[e] = (_Float16)slot[(j * 16 + la) * 16 + lg * 8 + e];
    }
    w4[j] = v;
  }
  f32x4 acc[4][4] = {};
#pragma unroll
  for (int i = 0; i < 4; ++i)
#pragma unroll
    for (int j = 0; j < 4; ++j)
      acc[i][j] = __builtin_amdgcn_mfma_f32_16x16x32_f16(a4[i], w4[j], acc[i][j], 0, 0, 0);
  __syncthreads();
#pragma unroll
  for (int i = 0; i < 4; ++i)
#pragma unroll
    for (int j = 0; j < 4; ++j)
#pragma unroll
      for (int r = 0; r < 4; ++r) {
        int t = i * 16 + lg * 4 + r, p = j * 16 + la;
        size_t ad = (size_t)(bl0 + t) * D_INNER + h * HEADDIM + p;
        ybuf[ad] = (_Float16)((float)ybuf[ad] + scq[t] * acc[i][j][r]);
      }
}

// ---------------------------------------------------------------------------
__global__ __launch_bounds__(256) void norm_kernel(
    const _Float16* __restrict__ y, _Float16* __restrict__ zx,
    const float* __restrict__ nw)
{
  const int row = blockIdx.x;
  const int tid = threadIdx.x;
  const _Float16* yr = y + (size_t)row * D_INNER;
  _Float16* zr = zx + (size_t)row * ZXP;
  float v[6];
  float ss = 0.f;
#pragma unroll
  for (int jj = 0; jj < 6; ++jj) {
    int c = jj * 256 + tid;
    float yv = (float)yr[c];
    float zv = (float)zr[c];
    float val = yv * fsilu(zv);
    v[jj] = val;
    ss = fmaf(val, val, ss);
  }
#pragma unroll
  for (int off = 32; off > 0; off >>= 1) ss += __shfl_xor(ss, off, 64);
  __shared__ float red[4];
  if ((tid & 63) == 0) red[tid >> 6] = ss;
  __syncthreads();
  float tot = red[0] + red[1] + red[2] + red[3];
  float rs = rsqrtf(tot * (1.f / 1536.f) + 1e-5f);
#pragma unroll
  for (int jj = 0; jj < 6; ++jj) {
    int c = jj * 256 + tid;
    zr[c] = (_Float16)(v[jj] * rs * nw[c]);
  }
}

// ---------------------------------------------------------------------------
extern "C" void kernel_launch(void* const* d_in, const int* in_sizes, int n_in,
                              void* d_out, int out_size, void* d_ws, size_t ws_size,
                              hipStream_t stream)
{
  const float* x_in = (const float*)d_in[0];
  const int*   tids = (const int*)d_in[1];
  const float* ipw  = (const float*)d_in[2];
  const float* cw   = (const float*)d_in[3];
  const float* cb   = (const float*)d_in[4];
  const float* dtb  = (const float*)d_in[5];
  const float* alog = (const float*)d_in[6];
  const float* Dv   = (const float*)d_in[7];
  const float* nw   = (const float*)d_in[8];
  const float* opw  = (const float*)d_in[9];
  const float* hw   = (const float*)d_in[10];
  const float* hb   = (const float*)d_in[11];
  const float* how  = (const float*)d_in[12];
  const float* hob  = (const float*)d_in[13];
  float* out = (float*)d_out;

  char* p = (char*)d_ws;
  _Float16* ipw_b = (_Float16*)p; p += (size_t)14413824 * 2;
  _Float16* opw_b = (_Float16*)p; p += (size_t)7077888 * 2;
  _Float16* hw_b  = (_Float16*)p; p += (size_t)1179648 * 2;
  _Float16* how_b = (_Float16*)p; p += (size_t)786432 * 2;
  float*    hob_p = (float*)p;    p += (size_t)1024 * 4;
  const size_t used_w = (size_t)(p - (char*)d_ws);
  const size_t PB = 54528000;
  int nb = 4;
  while (nb > 1 && used_w + (size_t)nb * PB > ws_size) nb >>= 1;

  cvt_kernel<<<8192, 256, 0, stream>>>(ipw, ipw_b, 14413824 / 4);
  cvt_kernel<<<6912, 256, 0, stream>>>(opw, opw_b, 7077888 / 4);
  cvt_kernel<<<1152, 256, 0, stream>>>(hw, hw_b, 1179648 / 4);
  pack_head_kernel<<<3072, 256, 0, stream>>>(how, hob, how_b, hob_p);

  for (int b0 = 0; b0 < BATCH; b0 += nb) {
    const int MT = nb * L_SEQ;
    _Float16* zx    = (_Float16*)p;
    _Float16* ybuf  = zx + (size_t)MT * ZXP;
    _Float16* bcbuf = ybuf + (size_t)MT * D_INNER;
    float*    Hseg  = (float*)(bcbuf + (size_t)MT * 32);
    float*    cumq  = Hseg + (size_t)nb * NHEADS * NSEG * 1024;
    _Float16* xbuf  = (_Float16*)(cumq + (size_t)MT * NHEADS);
    _Float16* hbuf  = zx;

    cvt_kernel<<<6144, 256, 0, stream>>>(x_in + (size_t)b0 * L_SEQ * DIMM,
                                         xbuf, (long)MT * DIMM / 4);

    for (int i = 0; i < 6; ++i) {
      gemm256<0><<<dim3(13, MT / 256), 512, 0, stream>>>(
          xbuf, DIMM, ipw_b + (size_t)i * D_IPROJ * DIMM, nullptr,
          zx, ZXP, MT, D_IPROJ, DIMM);
      ssdA_kernel<<<nb * NHEADS * NSEG, 64, 0, stream>>>(
          zx, cw + (size_t)i * CONVD * 4, cb + i * CONVD,
          dtb + i * NHEADS, alog + i * NHEADS, Dv + i * NHEADS,
          ybuf, bcbuf, Hseg, cumq);
      scanB_kernel<<<nb * NHEADS, 1024, 0, stream>>>(Hseg, cumq);
      ssdC_kernel<<<nb * NHEADS * NSEG, 64, 0, stream>>>(ybuf, bcbuf, Hseg, cumq);
      norm_kernel<<<MT, 256, 0, stream>>>(ybuf, zx, nw + i * D_INNER);
      gemm256<0><<<dim3(3, MT / 256), 512, 0, stream>>>(
          zx, ZXP, opw_b + (size_t)i * DIMM * D_INNER, nullptr,
          xbuf, DIMM, MT, DIMM, D_INNER);
    }

    for (int t = 0; t < 2; ++t) {
      gemm256<2><<<dim3(3, MT / 256), 512, 0, stream>>>(
          xbuf, DIMM, hw_b + (size_t)t * DIMM * DIMM, hb + t * DIMM,
          hbuf, DIMM, MT, DIMM, DIMM);
      gemm_mfma<3><<<dim3(4, MT / 128), 256, 0, stream>>>(
          hbuf, DIMM, how_b + (size_t)t * 512 * DIMM, hob_p + t * 512,
          out + (size_t)t * 4 * 16384 * 128 + (size_t)b0 * L_SEQ * 128,
          128, (long)16384 * 128, MT, 512, DIMM,
          tids + (size_t)b0 * L_SEQ, t);
    }
  }
}

// Round 18
// 1782.771 us; speedup vs baseline: 1.1449x; 1.0475x over previous
//
#include <hip/hip_runtime.h>
#include <cstdint>
#include <cstddef>

#define L_SEQ   4096
#define BATCH   4
#define DIMM    768
#define D_INNER 1536
#define NHEADS  24
#define HEADDIM 64
#define D_STATE 16
#define CONVD   1568
#define D_IPROJ 3128
#define ZXP     3200     // padded zx row stride (6400B = 64B-aligned rows)
#define SEGLEN  64
#define NSEG    (L_SEQ / SEGLEN)   // 64
#define BCP     44       // BC LDS row stride (conflict-free, 8B-aligned)

typedef _Float16 f16x8 __attribute__((ext_vector_type(8)));
typedef _Float16 f16x4 __attribute__((ext_vector_type(4)));
typedef float    f32x4 __attribute__((ext_vector_type(4)));

__device__ __forceinline__ void glds16(const _Float16* g, _Float16* l) {
  __builtin_amdgcn_global_load_lds(
      (__attribute__((address_space(1))) unsigned int*)g,
      (__attribute__((address_space(3))) unsigned int*)l, 16, 0, 0);
}

__device__ __forceinline__ float fsilu(float x) {
  return x * __builtin_amdgcn_rcpf(1.f + __expf(-x));
}
__device__ __forceinline__ float fsig(float x) {
  return __builtin_amdgcn_rcpf(1.f + __expf(-x));
}

// ---------------------------------------------------------------------------
// f16 MFMA GEMM (128x128x64, 4 waves): global_load_lds staging, XOR swizzle
// via pre-swizzled global source, XCD-band swizzle, LDS-transpose epilogue.
// OM: 0 = f16 out (+ col<N guard), 2 = f16 out + f32 bias,
//     3 = f32 out + bias + sigmoid(q>0) + type-mask (head fusion; N=512)
// ---------------------------------------------------------------------------
template <int OM>
__global__ __launch_bounds__(256, 2) void gemm_mfma(
    const _Float16* __restrict__ A, int lda,
    const _Float16* __restrict__ W,
    const float* __restrict__ bias,
    void* __restrict__ Cv, long ldc, long extra,
    int M, int N, int K,
    const int* __restrict__ tidsp, int thead)
{
  __shared__ __align__(16) char smem[33792];
  _Float16* As = (_Float16*)smem;
  _Float16* Ws = (_Float16*)(smem + 16384);
  const int tid = threadIdx.x;
  const int lane = tid & 63, wid = tid >> 6;
  const int wr = wid >> 1, wc = wid & 1;

  const int nbx = gridDim.x, nby = gridDim.y;
  const int flat = blockIdx.y * nbx + blockIdx.x;
  const int xcd = flat & 7;
  const int bidx = flat >> 3;
  const int rpx = nby >> 3;
  const int rl = bidx % rpx;
  const int ct = bidx / rpx;
  const long m0 = (long)(xcd * rpx + rl) * 128;
  const int n0 = ct * 128;

  const int la = lane & 15, lg = lane >> 4;
  const int srow = lane >> 3, schunk = lane & 7;

  f32x4 acc[4][4] = {};

  for (int k0 = 0; k0 < K; k0 += 64) {
    __syncthreads();
#pragma unroll
    for (int p = 0; p < 4; ++p) {
      const int rg = (wid << 2) + p;
      const int row = (rg << 3) + srow;
      const int scn = schunk ^ (row & 7);
      glds16(A + (m0 + row) * (long)lda + k0 + scn * 8, As + rg * 512);
      int n = n0 + row; if (n >= N) n = N - 1;
      glds16(W + (long)n * K + k0 + scn * 8, Ws + rg * 512);
    }
    asm volatile("s_waitcnt vmcnt(0)" ::: "memory");
    __syncthreads();
#pragma unroll
    for (int ks = 0; ks < 2; ++ks) {
      const int cc = ks * 4 + lg;
      f16x8 af[4], bfr[4];
#pragma unroll
      for (int i = 0; i < 4; ++i) {
        int ra = wr * 64 + i * 16 + la;
        int rb = wc * 64 + i * 16 + la;
        af[i]  = *(const f16x8*)&As[ra * 64 + ((cc ^ (ra & 7)) << 3)];
        bfr[i] = *(const f16x8*)&Ws[rb * 64 + ((cc ^ (rb & 7)) << 3)];
      }
#pragma unroll
      for (int i = 0; i < 4; ++i)
#pragma unroll
        for (int j = 0; j < 4; ++j)
          acc[i][j] = __builtin_amdgcn_mfma_f32_16x16x32_f16(af[i], bfr[j], acc[i][j], 0, 0, 0);
    }
  }

  float* epi = (float*)smem;                    // [64][132]
#pragma unroll
  for (int ph = 0; ph < 2; ++ph) {
    __syncthreads();
    if (wr == ph) {
#pragma unroll
      for (int i = 0; i < 4; ++i)
#pragma unroll
        for (int j = 0; j < 4; ++j)
#pragma unroll
          for (int r = 0; r < 4; ++r)
            epi[(i * 16 + lg * 4 + r) * 132 + wc * 64 + j * 16 + la] = acc[i][j][r];
    }
    __syncthreads();
    if (OM == 3) {
      const int q = n0 >> 7;
      const int rr = tid >> 5;
      const int ch = tid & 31;
#pragma unroll
      for (int ps = 0; ps < 8; ++ps) {
        int lrow = ps * 8 + rr;
        long gr = m0 + ph * 64 + lrow;
        float keep = (tidsp[gr] == thead) ? 1.f : 0.f;
        float4 v = *(float4*)&epi[lrow * 132 + ch * 4];
        float o[4] = {v.x, v.y, v.z, v.w};
#pragma unroll
        for (int e = 0; e < 4; ++e) {
          float vv = o[e] + bias[n0 + ch * 4 + e];
          if (q != 0) vv = fsig(vv);
          o[e] = vv * keep;
        }
        *(float4*)((float*)Cv + (long)q * extra + gr * 128 + ch * 4) =
            make_float4(o[0], o[1], o[2], o[3]);
      }
    } else {
      const int rr = tid >> 4;
      const int ch = tid & 15;
      const int col = n0 + ch * 8;
      float b[8] = {0.f, 0.f, 0.f, 0.f, 0.f, 0.f, 0.f, 0.f};
      if (OM == 2 && col < N) {
#pragma unroll
        for (int e = 0; e < 8; ++e) b[e] = bias[col + e];
      }
#pragma unroll
      for (int ps = 0; ps < 4; ++ps) {
        int lrow = ps * 16 + rr;
        long gr = m0 + ph * 64 + lrow;
        if (col < N) {
          float4 v0 = *(float4*)&epi[lrow * 132 + ch * 8];
          float4 v1 = *(float4*)&epi[lrow * 132 + ch * 8 + 4];
          f16x8 o = {(_Float16)(v0.x + b[0]), (_Float16)(v0.y + b[1]),
                     (_Float16)(v0.z + b[2]), (_Float16)(v0.w + b[3]),
                     (_Float16)(v1.x + b[4]), (_Float16)(v1.y + b[5]),
                     (_Float16)(v1.z + b[6]), (_Float16)(v1.w + b[7])};
          *(f16x8*)((_Float16*)Cv + gr * ldc + col) = o;
        }
      }
    }
  }
}

// ---------------------------------------------------------------------------
__global__ __launch_bounds__(256) void cvt_kernel(
    const float* __restrict__ src, _Float16* __restrict__ dst, long n4)
{
  long i = (long)blockIdx.x * 256 + threadIdx.x;
  long stride = (long)gridDim.x * 256;
  for (; i < n4; i += stride) {
    float4 v = *(const float4*)(src + i * 4);
    f16x4 o = { (_Float16)v.x, (_Float16)v.y, (_Float16)v.z, (_Float16)v.w };
    *(f16x4*)(dst + i * 4) = o;
  }
}

__global__ __launch_bounds__(256) void pack_head_kernel(
    const float* __restrict__ how, const float* __restrict__ hob,
    _Float16* __restrict__ howb, float* __restrict__ hobp)
{
  const int wmap[4] = {0, 3, 1, 2};
  int idx = blockIdx.x * 256 + threadIdx.x;
  if (idx < 2 * 512 * 768) {
    int t = idx / (512 * 768);
    int rem = idx - t * 512 * 768;
    int q = rem / (128 * 768);
    int rem2 = rem - q * 128 * 768;
    howb[idx] = (_Float16)how[((size_t)(t * 4 + wmap[q])) * 128 * 768 + rem2];
  }
  if (idx < 1024) {
    int t = idx >> 9, rem = idx & 511;
    int q = rem >> 7, pp = rem & 127;
    hobp[idx] = hob[(t * 4 + wmap[q]) * 128 + pp];
  }
}

// ---------------------------------------------------------------------------
// SSD pass A (v3): log2-domain decay, fast silu, BC stride 44.
// ---------------------------------------------------------------------------
__global__ __launch_bounds__(64) void ssdA_kernel(
    const _Float16* __restrict__ zx, const float* __restrict__ cw,
    const float* __restrict__ cb, const float* __restrict__ dtb,
    const float* __restrict__ alog, const float* __restrict__ Dv,
    _Float16* __restrict__ ybuf, _Float16* __restrict__ bcbuf,
    float* __restrict__ Hseg, float* __restrict__ cumq)
{
  __shared__ __align__(16) char sm[14848];
  _Float16* XV    = (_Float16*)sm;           // [64][66] xconv (row=t)
  _Float16* bcraw = (_Float16*)sm;           // [67][32] alias (dead before XV)
  _Float16* BC    = (_Float16*)(sm + 8448);  // [64][BCP]: B 0..15, C 16..31
  float* sa  = (float*)(sm + 14080);         // log2-domain prefix decay
  float* sdt = (float*)(sm + 14336);
  float* sws = (float*)(sm + 14592);         // w[s]*dt[s]
  const int lane = threadIdx.x;
  const int seg = blockIdx.x & (NSEG - 1);
  const int bh = blockIdx.x >> 6;
  const int h = bh % NHEADS, b = bh / NHEADS;
  const int bl0 = b * L_SEQ + seg * SEGLEN;
  const float LOG2E = 1.44269504088896f;

  for (int i = lane; i < 67 * 4; i += 64) {
    int r = i >> 2, q = (i & 3) << 3;
    f16x8 v = {};
    if (seg > 0 || r >= 3)
      v = *(const f16x8*)&zx[(size_t)(bl0 - 3 + r) * ZXP + 2 * D_INNER + q];
    *(f16x8*)&bcraw[r * 32 + q] = v;
  }
  {
    float raw = (float)zx[(size_t)(bl0 + lane) * ZXP + (D_INNER + CONVD) + h] + dtb[h];
    float sp = (raw > 20.f) ? raw : log1pf(__expf(raw));
    sdt[lane] = sp;
    float av = __expf(alog[h]) * sp * LOG2E;   // log2-domain
#pragma unroll
    for (int off = 1; off < 64; off <<= 1) {
      float tv = __shfl_up(av, off, 64);
      if (lane >= off) av += tv;
    }
    sa[lane] = av;
    cumq[(size_t)bh * L_SEQ + seg * SEGLEN + lane] = exp2f(-av);
    float alast = __shfl(av, 63, 64);
    sws[lane] = exp2f(av - alast) * sp;
  }
  __syncthreads();

  for (int i = lane; i < SEGLEN * 32; i += 64) {
    int t = i >> 5, c = i & 31;
    float acc = cb[D_INNER + c];
#pragma unroll
    for (int k = 0; k < 4; ++k)
      acc = fmaf(cw[(D_INNER + c) * 4 + k], (float)bcraw[(t + k) * 32 + c], acc);
    _Float16 sh = (_Float16)fsilu(acc);
    BC[t * BCP + c] = sh;
    bcbuf[(size_t)(bl0 + t) * 32 + c] = sh;
  }
  __syncthreads();   // bcraw dead -> XV region reusable

  const int xch = h * HEADDIM + lane;
  const _Float16* xg = zx + (size_t)bl0 * ZXP + D_INNER + xch;
  const float cwx0 = cw[xch * 4 + 0], cwx1 = cw[xch * 4 + 1];
  const float cwx2 = cw[xch * 4 + 2], cwx3 = cw[xch * 4 + 3];
  const float cbx = cb[xch];
  float xw0 = 0.f, xw1 = 0.f, xw2 = 0.f;
  if (seg > 0) {
    xw0 = (float)xg[-3 * (long)ZXP];
    xw1 = (float)xg[-2 * (long)ZXP];
    xw2 = (float)xg[-1 * (long)ZXP];
  }
  float xcur = (float)xg[0];
  for (int t = 0; t < SEGLEN; ++t) {
    float xnext = (t < SEGLEN - 1) ? (float)xg[(size_t)(t + 1) * ZXP] : 0.f;
    float xa = cbx;
    xa = fmaf(cwx0, xw0, xa);
    xa = fmaf(cwx1, xw1, xa);
    xa = fmaf(cwx2, xw2, xa);
    xa = fmaf(cwx3, xcur, xa);
    XV[t * 66 + lane] = (_Float16)fsilu(xa);
    xw0 = xw1; xw1 = xw2; xw2 = xcur; xcur = xnext;
  }
  __syncthreads();

  const int la = lane & 15, lg = lane >> 4;

  f16x4 Mfrag[4][4];
  {
    f16x4 cf[4];
    float sat[4];
#pragma unroll
    for (int tt = 0; tt < 4; ++tt) {
      cf[tt] = *(const f16x4*)&BC[(tt * 16 + la) * BCP + 16 + lg * 4];
      sat[tt] = sa[tt * 16 + la];
    }
#pragma unroll
    for (int st = 0; st < 4; ++st) {
      f16x4 bfA = *(const f16x4*)&BC[(st * 16 + la) * BCP + lg * 4];
#pragma unroll
      for (int tt = 0; tt < 4; ++tt) {
        f32x4 a1 = {};
        a1 = __builtin_amdgcn_mfma_f32_16x16x16f16(bfA, cf[tt], a1, 0, 0, 0);
        f16x4 m;
#pragma unroll
        for (int r = 0; r < 4; ++r) {
          int s = st * 16 + lg * 4 + r;
          int t = tt * 16 + la;
          float mv = 0.f;
          if (s <= t) mv = a1[r] * exp2f(sa[s] - sat[tt]);
          m[r] = (_Float16)mv;
        }
        Mfrag[st][tt] = m;
      }
    }
  }

  f16x4 b3[4];
#pragma unroll
  for (int st = 0; st < 4; ++st) {
    f16x4 v;
#pragma unroll
    for (int e = 0; e < 4; ++e)
      v[e] = BC[(st * 16 + lg * 4 + e) * BCP + la];
    b3[st] = v;
  }

  const float Dh = Dv[h];
  float* Hst = Hseg + ((size_t)bh * NSEG + seg) * 1024;
#pragma unroll
  for (int pt = 0; pt < 4; ++pt) {
    f16x4 bf[4], af3[4];
#pragma unroll
    for (int st = 0; st < 4; ++st) {
      f16x4 v, w;
#pragma unroll
      for (int e = 0; e < 4; ++e) {
        int s = st * 16 + lg * 4 + e;
        float xv = (float)XV[s * 66 + pt * 16 + la];
        v[e] = (_Float16)(xv * sdt[s]);
        w[e] = (_Float16)(xv * sws[s]);
      }
      bf[st] = v; af3[st] = w;
    }
#pragma unroll
    for (int tt = 0; tt < 4; ++tt) {
      f32x4 a2 = {};
#pragma unroll
      for (int st = 0; st < 4; ++st)
        a2 = __builtin_amdgcn_mfma_f32_16x16x16f16(Mfrag[st][tt], bf[st], a2, 0, 0, 0);
#pragma unroll
      for (int r = 0; r < 4; ++r) {
        int t = tt * 16 + lg * 4 + r, p = pt * 16 + la;
        float y = a2[r] + Dh * (float)XV[t * 66 + p];
        ybuf[(size_t)(bl0 + t) * D_INNER + h * HEADDIM + p] = (_Float16)y;
      }
    }
    f32x4 a3 = {};
#pragma unroll
    for (int st = 0; st < 4; ++st)
      a3 = __builtin_amdgcn_mfma_f32_16x16x16f16(af3[st], b3[st], a3, 0, 0, 0);
#pragma unroll
    for (int r = 0; r < 4; ++r) {
      int p = pt * 16 + lg * 4 + r;
      Hst[p * 16 + la] = a3[r];
    }
  }
}

// ---------------------------------------------------------------------------
__global__ __launch_bounds__(1024) void scanB_kernel(
    float* __restrict__ Hseg, const float* __restrict__ cumq)
{
  const int bh = blockIdx.x;
  const int t = threadIdx.x;
  __shared__ float sp[NSEG];
  if (t < NSEG) sp[t] = cumq[(size_t)bh * L_SEQ + t * SEGLEN + (SEGLEN - 1)];
  __syncthreads();
  float v[NSEG];
#pragma unroll
  for (int s = 0; s < NSEG; ++s)
    v[s] = Hseg[((size_t)bh * NSEG + s) * 1024 + t];
  float h = 0.f;
#pragma unroll
  for (int s = 0; s < NSEG; ++s) {
    Hseg[((size_t)bh * NSEG + s) * 1024 + t] = h;
    h = fmaf(sp[s], h, v[s]);
  }
}

// ---------------------------------------------------------------------------
__global__ __launch_bounds__(64) void ssdC_kernel(
    _Float16* __restrict__ ybuf, const _Float16* __restrict__ bcbuf,
    const float* __restrict__ Hseg, const float* __restrict__ cumq)
{
  const int seg = blockIdx.x & (NSEG - 1);
  if (seg == 0) return;
  const int lane = threadIdx.x;
  const int bh = blockIdx.x >> 6;
  const int h = bh % NHEADS, b = bh / NHEADS;
  const int bl0 = b * L_SEQ + seg * SEGLEN;
  __shared__ float scq[SEGLEN];
  scq[lane] = cumq[(size_t)bh * L_SEQ + seg * SEGLEN + lane];
  const int la = lane & 15, lg = lane >> 4;
  const float* slot = Hseg + ((size_t)bh * NSEG + seg) * 1024;

  f16x8 a4[4], w4[4];
#pragma unroll
  for (int i = 0; i < 4; ++i) {
    f16x8 v = {};
    if (lg < 2)
      v = *(const f16x8*)&bcbuf[(size_t)(bl0 + i * 16 + la) * 32 + 16 + lg * 8];
    a4[i] = v;
  }
#pragma unroll
  for (int j = 0; j < 4; ++j) {
    f16x8 v = {};
    if (lg < 2) {
#pragma unroll
      for (int e = 0; e < 8; ++e)
        v[e] = (_Float16)slot[(j * 16 + la) * 16 + lg * 8 + e];
    }
    w4[j] = v;
  }
  f32x4 acc[4][4] = {};
#pragma unroll
  for (int i = 0; i < 4; ++i)
#pragma unroll
    for (int j = 0; j < 4; ++j)
      acc[i][j] = __builtin_amdgcn_mfma_f32_16x16x32_f16(a4[i], w4[j], acc[i][j], 0, 0, 0);
  __syncthreads();
#pragma unroll
  for (int i = 0; i < 4; ++i)
#pragma unroll
    for (int j = 0; j < 4; ++j)
#pragma unroll
      for (int r = 0; r < 4; ++r) {
        int t = i * 16 + lg * 4 + r, p = j * 16 + la;
        size_t ad = (size_t)(bl0 + t) * D_INNER + h * HEADDIM + p;
        ybuf[ad] = (_Float16)((float)ybuf[ad] + scq[t] * acc[i][j][r]);
      }
}

// ---------------------------------------------------------------------------
__global__ __launch_bounds__(256) void norm_kernel(
    const _Float16* __restrict__ y, _Float16* __restrict__ zx,
    const float* __restrict__ nw)
{
  const int row = blockIdx.x;
  const int tid = threadIdx.x;
  const _Float16* yr = y + (size_t)row * D_INNER;
  _Float16* zr = zx + (size_t)row * ZXP;
  float v[6];
  float ss = 0.f;
#pragma unroll
  for (int jj = 0; jj < 6; ++jj) {
    int c = jj * 256 + tid;
    float yv = (float)yr[c];
    float zv = (float)zr[c];
    float val = yv * fsilu(zv);
    v[jj] = val;
    ss = fmaf(val, val, ss);
  }
#pragma unroll
  for (int off = 32; off > 0; off >>= 1) ss += __shfl_xor(ss, off, 64);
  __shared__ float red[4];
  if ((tid & 63) == 0) red[tid >> 6] = ss;
  __syncthreads();
  float tot = red[0] + red[1] + red[2] + red[3];
  float rs = rsqrtf(tot * (1.f / 1536.f) + 1e-5f);
#pragma unroll
  for (int jj = 0; jj < 6; ++jj) {
    int c = jj * 256 + tid;
    zr[c] = (_Float16)(v[jj] * rs * nw[c]);
  }
}

// ---------------------------------------------------------------------------
extern "C" void kernel_launch(void* const* d_in, const int* in_sizes, int n_in,
                              void* d_out, int out_size, void* d_ws, size_t ws_size,
                              hipStream_t stream)
{
  const float* x_in = (const float*)d_in[0];
  const int*   tids = (const int*)d_in[1];
  const float* ipw  = (const float*)d_in[2];
  const float* cw   = (const float*)d_in[3];
  const float* cb   = (const float*)d_in[4];
  const float* dtb  = (const float*)d_in[5];
  const float* alog = (const float*)d_in[6];
  const float* Dv   = (const float*)d_in[7];
  const float* nw   = (const float*)d_in[8];
  const float* opw  = (const float*)d_in[9];
  const float* hw   = (const float*)d_in[10];
  const float* hb   = (const float*)d_in[11];
  const float* how  = (const float*)d_in[12];
  const float* hob  = (const float*)d_in[13];
  float* out = (float*)d_out;

  char* p = (char*)d_ws;
  _Float16* ipw_b = (_Float16*)p; p += (size_t)14413824 * 2;
  _Float16* opw_b = (_Float16*)p; p += (size_t)7077888 * 2;
  _Float16* hw_b  = (_Float16*)p; p += (size_t)1179648 * 2;
  _Float16* how_b = (_Float16*)p; p += (size_t)786432 * 2;
  float*    hob_p = (float*)p;    p += (size_t)1024 * 4;
  const size_t used_w = (size_t)(p - (char*)d_ws);
  const size_t PB = 54528000;
  int nb = 4;
  while (nb > 1 && used_w + (size_t)nb * PB > ws_size) nb >>= 1;

  cvt_kernel<<<8192, 256, 0, stream>>>(ipw, ipw_b, 14413824 / 4);
  cvt_kernel<<<6912, 256, 0, stream>>>(opw, opw_b, 7077888 / 4);
  cvt_kernel<<<1152, 256, 0, stream>>>(hw, hw_b, 1179648 / 4);
  pack_head_kernel<<<3072, 256, 0, stream>>>(how, hob, how_b, hob_p);

  for (int b0 = 0; b0 < BATCH; b0 += nb) {
    const int MT = nb * L_SEQ;
    _Float16* zx    = (_Float16*)p;
    _Float16* ybuf  = zx + (size_t)MT * ZXP;
    _Float16* bcbuf = ybuf + (size_t)MT * D_INNER;
    float*    Hseg  = (float*)(bcbuf + (size_t)MT * 32);
    float*    cumq  = Hseg + (size_t)nb * NHEADS * NSEG * 1024;
    _Float16* xbuf  = (_Float16*)(cumq + (size_t)MT * NHEADS);
    _Float16* hbuf  = zx;

    cvt_kernel<<<6144, 256, 0, stream>>>(x_in + (size_t)b0 * L_SEQ * DIMM,
                                         xbuf, (long)MT * DIMM / 4);

    for (int i = 0; i < 6; ++i) {
      gemm_mfma<0><<<dim3((D_IPROJ + 127) / 128, MT / 128), 256, 0, stream>>>(
          xbuf, DIMM, ipw_b + (size_t)i * D_IPROJ * DIMM, nullptr,
          zx, ZXP, 0, MT, D_IPROJ, DIMM, nullptr, 0);
      ssdA_kernel<<<nb * NHEADS * NSEG, 64, 0, stream>>>(
          zx, cw + (size_t)i * CONVD * 4, cb + i * CONVD,
          dtb + i * NHEADS, alog + i * NHEADS, Dv + i * NHEADS,
          ybuf, bcbuf, Hseg, cumq);
      scanB_kernel<<<nb * NHEADS, 1024, 0, stream>>>(Hseg, cumq);
      ssdC_kernel<<<nb * NHEADS * NSEG, 64, 0, stream>>>(ybuf, bcbuf, Hseg, cumq);
      norm_kernel<<<MT, 256, 0, stream>>>(ybuf, zx, nw + i * D_INNER);
      gemm_mfma<0><<<dim3(DIMM / 128, MT / 128), 256, 0, stream>>>(
          zx, ZXP, opw_b + (size_t)i * DIMM * D_INNER, nullptr,
          xbuf, DIMM, 0, MT, DIMM, D_INNER, nullptr, 0);
    }

    for (int t = 0; t < 2; ++t) {
      gemm_mfma<2><<<dim3(DIMM / 128, MT / 128), 256, 0, stream>>>(
          xbuf, DIMM, hw_b + (size_t)t * DIMM * DIMM, hb + t * DIMM,
          hbuf, DIMM, 0, MT, DIMM, DIMM, nullptr, 0);
      gemm_mfma<3><<<dim3(4, MT / 128), 256, 0, stream>>>(
          hbuf, DIMM, how_b + (size_t)t * 512 * DIMM, hob_p + t * 512,
          out + (size_t)t * 4 * 16384 * 128 + (size_t)b0 * L_SEQ * 128,
          128, (long)16384 * 128, MT, 512, DIMM,
          tids + (size_t)b0 * L_SEQ, t);
    }
  }
}